// Round 2
// baseline (1728.794 us; speedup 1.0000x reference)
//
#include <hip/hip_runtime.h>
#include <stdint.h>

#define D_IN  128
#define D_OUT 64
#define NEG_SLOPE 0.2f

// ---------------------------------------------------------------------------
// Fused skinny GEMM + attention score (wave per row, w staged in LDS).
// ---------------------------------------------------------------------------
__global__ void msg_score_kernel(const float* __restrict__ x,
                                 const float* __restrict__ w,
                                 const float* __restrict__ att, int att_off,
                                 float* __restrict__ msg,
                                 float* __restrict__ score,
                                 int n_rows) {
    __shared__ float wl[D_IN * D_OUT];
    const int tid = threadIdx.x;

    const float4* w4  = (const float4*)w;
    float4*       wl4 = (float4*)wl;
    for (int i = tid; i < (D_IN * D_OUT) / 4; i += blockDim.x) wl4[i] = w4[i];
    __syncthreads();

    const int gtid = blockIdx.x * blockDim.x + tid;
    const int row  = gtid >> 6;
    const int j    = tid & 63;
    if (row >= n_rows) return;

    const float4* x4 = (const float4*)(x + (size_t)row * D_IN);
    float acc = 0.f;
#pragma unroll
    for (int k4 = 0; k4 < D_IN / 4; ++k4) {
        float4 xv = x4[k4];
        acc += xv.x * wl[(k4 * 4 + 0) * D_OUT + j];
        acc += xv.y * wl[(k4 * 4 + 1) * D_OUT + j];
        acc += xv.z * wl[(k4 * 4 + 2) * D_OUT + j];
        acc += xv.w * wl[(k4 * 4 + 3) * D_OUT + j];
    }
    msg[(size_t)row * D_OUT + j] = acc;

    float v = acc * att[att_off + j];
#pragma unroll
    for (int off = 32; off > 0; off >>= 1) v += __shfl_down(v, off, 64);
    if (j == 0) score[row] = v;
}

// ---------------------------------------------------------------------------
// Histogram of row/col keys (counts feed the counting sort).
// ---------------------------------------------------------------------------
__global__ void hist_kernel(const int* __restrict__ row_idx,
                            const int* __restrict__ col_idx,
                            int* __restrict__ row_cnt,
                            int* __restrict__ col_cnt, int nnz) {
    const int i = blockIdx.x * blockDim.x + threadIdx.x;
    if (i >= nnz) return;
    atomicAdd(&row_cnt[row_idx[i]], 1);
    atomicAdd(&col_cnt[col_idx[i]], 1);
}

// ---------------------------------------------------------------------------
// Single-block exclusive scan: cnt[] (in: counts) -> off[] (exclusive offsets,
// n+1 entries) and cnt[] (out: cursor copy of offsets for the sort scatter).
// One block of 1024 threads; each thread owns a contiguous chunk.
// ---------------------------------------------------------------------------
__global__ void scan_kernel(int* __restrict__ cnt, int* __restrict__ off, int n) {
    __shared__ int lds[1024];
    const int t = threadIdx.x;
    const int chunk = (n + 1023) / 1024;
    const int b = t * chunk;
    const int e = min(n, b + chunk);

    int s = 0;
    for (int j = b; j < e; ++j) s += cnt[j];
    lds[t] = s;
    __syncthreads();
    for (int d = 1; d < 1024; d <<= 1) {
        int v = (t >= d) ? lds[t - d] : 0;
        __syncthreads();
        lds[t] += v;
        __syncthreads();
    }
    int ex = lds[t] - s;   // exclusive prefix of this thread's chunk
    for (int j = b; j < e; ++j) {
        int c = cnt[j];
        off[j] = ex;
        cnt[j] = ex;       // cursor (aliases counts; safe: write-after-read per j)
        ex += c;
    }
    if (t == 1023) off[n] = lds[1023];
}

// ---------------------------------------------------------------------------
// Counting-sort scatter: place edge ids into row-sorted and col-sorted order.
// ---------------------------------------------------------------------------
__global__ void sort_kernel(const int* __restrict__ row_idx,
                            const int* __restrict__ col_idx,
                            int* __restrict__ row_cur,
                            int* __restrict__ col_cur,
                            int* __restrict__ se_row,
                            int* __restrict__ se_col, int nnz) {
    const int i = blockIdx.x * blockDim.x + threadIdx.x;
    if (i >= nnz) return;
    const int pr = atomicAdd(&row_cur[row_idx[i]], 1);
    se_row[pr] = i;
    const int pc = atomicAdd(&col_cur[col_idx[i]], 1);
    se_col[pc] = i;
}

// ---------------------------------------------------------------------------
// Segmented accumulate, wave per output row. Pass 1: f64 segment sum in
// registers (deterministic, no atomics). Pass 2: gather other-side msg rows
// (256 B coalesced), scale by e/sum*nb, accumulate in one VGPR per lane,
// single plain store. Used for both outputs with roles swapped.
// ---------------------------------------------------------------------------
__global__ void accum_kernel(const int* __restrict__ off,
                             const int* __restrict__ sorted_eid,
                             const int* __restrict__ other_idx,
                             const float* __restrict__ nbhd,
                             const float* __restrict__ my_score,
                             const float* __restrict__ other_score,
                             const float* __restrict__ other_msg,
                             float* __restrict__ out, int n_mine) {
    const int wave = (int)((blockIdx.x * (size_t)blockDim.x + threadIdx.x) >> 6);
    const int lane = threadIdx.x & 63;
    if (wave >= n_mine) return;

    const int beg = off[wave];
    const int end = off[wave + 1];
    const float my = my_score[wave];

    // pass 1: f64 segment sum (lanes stride edges)
    double psum = 0.0;
    for (int k = beg + lane; k < end; k += 64) {
        const int eid = sorted_eid[k];
        const float xv = other_score[other_idx[eid]] + my;
        psum += (double)(xv >= 0.f ? xv : NEG_SLOPE * xv);
    }
#pragma unroll
    for (int o = 32; o > 0; o >>= 1) psum += __shfl_down(psum, o, 64);
    double ers = __shfl(psum, 0, 64);
    if (ers == 0.0) ers = 1.0;
    const double inv = 1.0 / ers;

    // pass 2: one edge per iteration, software-pipelined scalar loads
    float acc = 0.f;
    int   eid_n = 0, o_n = 0;
    float os_n = 0.f, nb_n = 0.f;
    if (beg < end) {
        eid_n = sorted_eid[beg];
        o_n   = other_idx[eid_n];
        os_n  = other_score[o_n];
        nb_n  = nbhd[eid_n];
    }
    for (int k = beg; k < end; ) {
        const int   o  = o_n;
        const float os = os_n;
        const float nb = nb_n;
        ++k;
        if (k < end) {           // prefetch next edge's scalars
            eid_n = sorted_eid[k];
            o_n   = other_idx[eid_n];
            os_n  = other_score[o_n];
            nb_n  = nbhd[eid_n];
        }
        const float xv = os + my;
        const float e  = xv >= 0.f ? xv : NEG_SLOPE * xv;
        const float wt = (float)((double)e * inv) * nb;
        acc += wt * other_msg[(size_t)o * D_OUT + lane];
    }
    out[(size_t)wave * D_OUT + lane] = acc;
}

// ---------------------------------------------------------------------------
extern "C" void kernel_launch(void* const* d_in, const int* in_sizes, int n_in,
                              void* d_out, int out_size, void* d_ws, size_t ws_size,
                              hipStream_t stream) {
    const float* x_source = (const float*)d_in[0];
    const float* x_target = (const float*)d_in[1];
    const float* nbhd     = (const float*)d_in[2];
    const float* w_s      = (const float*)d_in[3];
    const float* w_t      = (const float*)d_in[4];
    const float* att      = (const float*)d_in[5];
    const int*   row_idx  = (const int*)d_in[6];
    const int*   col_idx  = (const int*)d_in[7];

    const int n_s = in_sizes[0] / D_IN;   // 100000
    const int n_t = in_sizes[1] / D_IN;   // 20000
    const int nnz = in_sizes[2];          // 2000000

    float* out = (float*)d_out;
    float* mos = out;                          // (n_s, 64)
    float* mot = out + (size_t)n_s * D_OUT;    // (n_t, 64)

    // workspace layout (~48 MB)
    char* ws = (char*)d_ws;
    float* s_msg   = (float*)ws;  ws += sizeof(float) * (size_t)n_s * D_OUT;
    float* t_msg   = (float*)ws;  ws += sizeof(float) * (size_t)n_t * D_OUT;
    float* s_score = (float*)ws;  ws += sizeof(float) * (size_t)n_s;
    float* t_score = (float*)ws;  ws += sizeof(float) * (size_t)n_t;
    int* row_cnt = (int*)ws;  ws += sizeof(int) * (size_t)n_t;       // -> cursor
    int* col_cnt = (int*)ws;  ws += sizeof(int) * (size_t)n_s;       // -> cursor
    int* row_off = (int*)ws;  ws += sizeof(int) * (size_t)(n_t + 1);
    int* col_off = (int*)ws;  ws += sizeof(int) * (size_t)(n_s + 1);
    int* se_row  = (int*)ws;  ws += sizeof(int) * (size_t)nnz;
    int* se_col  = (int*)ws;  ws += sizeof(int) * (size_t)nnz;

    // zero the histogram counters (row_cnt/col_cnt are contiguous)
    hipMemsetAsync(row_cnt, 0, sizeof(int) * (size_t)(n_t + n_s), stream);

    // 1) messages + scores
    msg_score_kernel<<<(n_s * 64 + 255) / 256, 256, 0, stream>>>(
        x_source, w_s, att, 0, s_msg, s_score, n_s);
    msg_score_kernel<<<(n_t * 64 + 255) / 256, 256, 0, stream>>>(
        x_target, w_t, att, D_OUT, t_msg, t_score, n_t);

    // 2) counting sort: hist -> scan -> scatter
    hist_kernel<<<(nnz + 255) / 256, 256, 0, stream>>>(
        row_idx, col_idx, row_cnt, col_cnt, nnz);
    scan_kernel<<<1, 1024, 0, stream>>>(row_cnt, row_off, n_t);
    scan_kernel<<<1, 1024, 0, stream>>>(col_cnt, col_off, n_s);
    sort_kernel<<<(nnz + 255) / 256, 256, 0, stream>>>(
        row_idx, col_idx, row_cnt, col_cnt, se_row, se_col, nnz);

    // 3) segmented accumulation, no output atomics
    accum_kernel<<<(int)(((size_t)n_t * 64 + 255) / 256), 256, 0, stream>>>(
        row_off, se_row, col_idx, nbhd, t_score, s_score, s_msg, mot, n_t);
    accum_kernel<<<(int)(((size_t)n_s * 64 + 255) / 256), 256, 0, stream>>>(
        col_off, se_col, row_idx, nbhd, s_score, t_score, t_msg, mos, n_s);
}

// Round 3
// 912.608 us; speedup vs baseline: 1.8943x; 1.8943x over previous
//
#include <hip/hip_runtime.h>
#include <stdint.h>

#define D_IN  128
#define D_OUT 64
#define NEG_SLOPE 0.2f
#define SUB       8      // sub-bins per key (atomic-contention divider)
#define SUB_SHIFT 3
#define SCAN_CHUNK 4096  // elements per scan block (256 thr x 16)

struct __align__(4) Pay { int o; float e; float nb; };   // 12 B

// ---------------------------------------------------------------------------
// Fused skinny GEMM + attention score (wave per row, w staged in LDS).
// ---------------------------------------------------------------------------
__global__ void msg_score_kernel(const float* __restrict__ x,
                                 const float* __restrict__ w,
                                 const float* __restrict__ att, int att_off,
                                 float* __restrict__ msg,
                                 float* __restrict__ score,
                                 int n_rows) {
    __shared__ float wl[D_IN * D_OUT];
    const int tid = threadIdx.x;

    const float4* w4  = (const float4*)w;
    float4*       wl4 = (float4*)wl;
    for (int i = tid; i < (D_IN * D_OUT) / 4; i += blockDim.x) wl4[i] = w4[i];
    __syncthreads();

    const int gtid = blockIdx.x * blockDim.x + tid;
    const int row  = gtid >> 6;
    const int j    = tid & 63;
    if (row >= n_rows) return;

    const float4* x4 = (const float4*)(x + (size_t)row * D_IN);
    float acc = 0.f;
#pragma unroll
    for (int k4 = 0; k4 < D_IN / 4; ++k4) {
        float4 xv = x4[k4];
        acc += xv.x * wl[(k4 * 4 + 0) * D_OUT + j];
        acc += xv.y * wl[(k4 * 4 + 1) * D_OUT + j];
        acc += xv.z * wl[(k4 * 4 + 2) * D_OUT + j];
        acc += xv.w * wl[(k4 * 4 + 3) * D_OUT + j];
    }
    msg[(size_t)row * D_OUT + j] = acc;

    float v = acc * att[att_off + j];
#pragma unroll
    for (int off = 32; off > 0; off >>= 1) v += __shfl_down(v, off, 64);
    if (j == 0) score[row] = v;
}

// ---------------------------------------------------------------------------
// Sub-binned histogram over the unified (rows ++ cols) counter array.
// ---------------------------------------------------------------------------
__global__ void hist_kernel(const int* __restrict__ row_idx,
                            const int* __restrict__ col_idx,
                            int* __restrict__ cnt, int col_base, int nnz) {
    const int i = blockIdx.x * blockDim.x + threadIdx.x;
    if (i >= nnz) return;
    const int s = i & (SUB - 1);
    atomicAdd(&cnt[(row_idx[i] << SUB_SHIFT) + s], 1);
    atomicAdd(&cnt[col_base + (col_idx[i] << SUB_SHIFT) + s], 1);
}

// ---------------------------------------------------------------------------
// Hierarchical exclusive scan, 3 stages.
// ---------------------------------------------------------------------------
__global__ void scan_stage1(const int* __restrict__ cnt, int* __restrict__ bsum,
                            int n) {
    __shared__ int lds[256];
    const int t = threadIdx.x;
    const int base = blockIdx.x * SCAN_CHUNK;
    int s = 0;
    for (int k = t; k < SCAN_CHUNK; k += 256) {
        const int j = base + k;
        if (j < n) s += cnt[j];
    }
    lds[t] = s;
    __syncthreads();
    for (int d = 128; d > 0; d >>= 1) {
        if (t < d) lds[t] += lds[t + d];
        __syncthreads();
    }
    if (t == 0) bsum[blockIdx.x] = lds[0];
}

__global__ void scan_stage2(int* __restrict__ bsum, int nb) {
    __shared__ int lds[1024];
    const int t = threadIdx.x;
    const int v = (t < nb) ? bsum[t] : 0;
    lds[t] = v;
    __syncthreads();
    for (int d = 1; d < 1024; d <<= 1) {
        int u = (t >= d) ? lds[t - d] : 0;
        __syncthreads();
        lds[t] += u;
        __syncthreads();
    }
    if (t < nb) bsum[t] = lds[t] - v;   // exclusive
}

__global__ void scan_stage3(const int* __restrict__ cnt,
                            const int* __restrict__ bsum,
                            int* __restrict__ off, int* __restrict__ cur,
                            int n, int total) {
    __shared__ int lds[256];
    const int t = threadIdx.x;
    const int base = blockIdx.x * SCAN_CHUNK + t * 16;
    int c[16];
    int s = 0;
#pragma unroll
    for (int k = 0; k < 16; ++k) {
        const int j = base + k;
        c[k] = (j < n) ? cnt[j] : 0;
        s += c[k];
    }
    lds[t] = s;
    __syncthreads();
    for (int d = 1; d < 256; d <<= 1) {
        int u = (t >= d) ? lds[t - d] : 0;
        __syncthreads();
        lds[t] += u;
        __syncthreads();
    }
    int ex = bsum[blockIdx.x] + lds[t] - s;
#pragma unroll
    for (int k = 0; k < 16; ++k) {
        const int j = base + k;
        if (j < n) { off[j] = ex; cur[j] = ex; ex += c[k]; }
    }
    if (blockIdx.x == 0 && t == 0) off[n] = total;
}

// ---------------------------------------------------------------------------
// Counting-sort scatter of edge PAYLOADS {other_idx, e, nb}. e is computed
// here once (scores are L2-resident). Sub-binned cursors cut same-address
// atomic chains by 8x. Within-key order is arbitrary (fp32 sum-order only).
// ---------------------------------------------------------------------------
__global__ void scatter_kernel(const int* __restrict__ row_idx,
                               const int* __restrict__ col_idx,
                               const float* __restrict__ nbhd,
                               const float* __restrict__ s_score,
                               const float* __restrict__ t_score,
                               int* __restrict__ cur, int col_base,
                               Pay* __restrict__ pay, int nnz) {
    const int i = blockIdx.x * blockDim.x + threadIdx.x;
    if (i >= nnz) return;
    const int r = row_idx[i];
    const int c = col_idx[i];
    const float xv = s_score[c] + t_score[r];
    const float e  = xv >= 0.f ? xv : NEG_SLOPE * xv;
    const float nb = nbhd[i];
    const int s = i & (SUB - 1);

    const int pr = atomicAdd(&cur[(r << SUB_SHIFT) + s], 1);
    Pay pe; pe.o = c; pe.e = e; pe.nb = nb;
    pay[pr] = pe;

    const int pc = atomicAdd(&cur[col_base + (c << SUB_SHIFT) + s], 1);
    pe.o = r;
    pay[pc] = pe;
}

// ---------------------------------------------------------------------------
// Segmented accumulate, wave per output row, sequential payload reads.
// Pass 1: f64 segment sum of e (register/shuffle, deterministic-enough).
// Pass 2: 64-edge chunks -- lanes load payload in parallel, then each edge's
// (o, wt) is shuffle-broadcast while all 64 lanes gather the 256 B msg row.
// Gathers are independent across the inner loop -> deep memory parallelism.
// ---------------------------------------------------------------------------
__global__ void accum_kernel(const int* __restrict__ off, int off_base,
                             const Pay* __restrict__ pay,
                             const float* __restrict__ other_msg,
                             float* __restrict__ out, int n_mine) {
    const int wave = (int)((blockIdx.x * (size_t)blockDim.x + threadIdx.x) >> 6);
    const int lane = threadIdx.x & 63;
    if (wave >= n_mine) return;

    const int beg = off[off_base + (wave << SUB_SHIFT)];
    const int end = off[off_base + (wave << SUB_SHIFT) + SUB];

    // pass 1: f64 sum of e over the segment
    double psum = 0.0;
    for (int k = beg + lane; k < end; k += 64) psum += (double)pay[k].e;
#pragma unroll
    for (int o = 32; o > 0; o >>= 1) psum += __shfl_down(psum, o, 64);
    double ers = __shfl(psum, 0, 64);
    if (ers == 0.0) ers = 1.0;
    const double inv = 1.0 / ers;

    // pass 2: chunked gather-accumulate
    float acc = 0.f;
    for (int kb = beg; kb < end; kb += 64) {
        const int k = kb + lane;
        int o = 0; float wt = 0.f;
        if (k < end) {
            Pay p = pay[k];
            o  = p.o;
            wt = (float)((double)p.e * inv) * p.nb;
        }
        const int cnt = min(64, end - kb);
        for (int j = 0; j < cnt; ++j) {
            const int   oj = __shfl(o,  j, 64);
            const float wj = __shfl(wt, j, 64);
            acc += wj * other_msg[((size_t)oj << 6) + lane];
        }
    }
    out[((size_t)wave << 6) + lane] = acc;
}

// ---------------------------------------------------------------------------
extern "C" void kernel_launch(void* const* d_in, const int* in_sizes, int n_in,
                              void* d_out, int out_size, void* d_ws, size_t ws_size,
                              hipStream_t stream) {
    const float* x_source = (const float*)d_in[0];
    const float* x_target = (const float*)d_in[1];
    const float* nbhd     = (const float*)d_in[2];
    const float* w_s      = (const float*)d_in[3];
    const float* w_t      = (const float*)d_in[4];
    const float* att      = (const float*)d_in[5];
    const int*   row_idx  = (const int*)d_in[6];
    const int*   col_idx  = (const int*)d_in[7];

    const int n_s = in_sizes[0] / D_IN;   // 100000
    const int n_t = in_sizes[1] / D_IN;   // 20000
    const int nnz = in_sizes[2];          // 2000000

    float* out = (float*)d_out;
    float* mos = out;                          // (n_s, 64)
    float* mot = out + (size_t)n_s * D_OUT;    // (n_t, 64)

    const int col_base = n_t * SUB;            // 160000
    const int n_cnt    = (n_t + n_s) * SUB;    // 960000
    const int total    = 2 * nnz;              // 4000000

    // workspace layout (~95 MB)
    char* ws = (char*)d_ws;
    float* s_msg   = (float*)ws;  ws += sizeof(float) * (size_t)n_s * D_OUT;
    float* t_msg   = (float*)ws;  ws += sizeof(float) * (size_t)n_t * D_OUT;
    float* s_score = (float*)ws;  ws += sizeof(float) * (size_t)n_s;
    float* t_score = (float*)ws;  ws += sizeof(float) * (size_t)n_t;
    int* cnt  = (int*)ws;  ws += sizeof(int) * (size_t)n_cnt;
    int* cur  = (int*)ws;  ws += sizeof(int) * (size_t)n_cnt;
    int* off  = (int*)ws;  ws += sizeof(int) * (size_t)(n_cnt + 1);
    int* bsum = (int*)ws;  ws += sizeof(int) * 1024;
    Pay* pay  = (Pay*)ws;  ws += sizeof(Pay) * (size_t)total;

    hipMemsetAsync(cnt, 0, sizeof(int) * (size_t)n_cnt, stream);

    // 1) messages + scores
    msg_score_kernel<<<(n_s * 64 + 255) / 256, 256, 0, stream>>>(
        x_source, w_s, att, 0, s_msg, s_score, n_s);
    msg_score_kernel<<<(n_t * 64 + 255) / 256, 256, 0, stream>>>(
        x_target, w_t, att, D_OUT, t_msg, t_score, n_t);

    // 2) counting sort: hist -> 3-stage scan -> payload scatter
    hist_kernel<<<(nnz + 255) / 256, 256, 0, stream>>>(
        row_idx, col_idx, cnt, col_base, nnz);

    const int nb = (n_cnt + SCAN_CHUNK - 1) / SCAN_CHUNK;   // 235
    scan_stage1<<<nb, 256, 0, stream>>>(cnt, bsum, n_cnt);
    scan_stage2<<<1, 1024, 0, stream>>>(bsum, nb);
    scan_stage3<<<nb, 256, 0, stream>>>(cnt, bsum, off, cur, n_cnt, total);

    scatter_kernel<<<(nnz + 255) / 256, 256, 0, stream>>>(
        row_idx, col_idx, nbhd, s_score, t_score, cur, col_base, pay, nnz);

    // 3) segmented accumulation, no output atomics, sequential payload
    accum_kernel<<<(int)(((size_t)n_t * 64 + 255) / 256), 256, 0, stream>>>(
        off, 0, pay, s_msg, mot, n_t);
    accum_kernel<<<(int)(((size_t)n_s * 64 + 255) / 256), 256, 0, stream>>>(
        off, col_base, pay, t_msg, mos, n_s);
}

// Round 4
// 810.563 us; speedup vs baseline: 2.1328x; 1.1259x over previous
//
#include <hip/hip_runtime.h>
#include <stdint.h>

#define D_IN  128
#define D_OUT 64
#define NEG_SLOPE 0.2f
#define SUB       8      // sub-bins per key (atomic-contention divider)
#define SUB_SHIFT 3
#define SCAN_CHUNK 4096  // elements per scan block (256 thr x 16)

// payload record: {o_idx (as float bits), e, nb, pad} -- 16 B, float4-aligned
// so every scattered write is one dwordx4 that never straddles a 64 B line.

// ---------------------------------------------------------------------------
// Fused skinny GEMM + attention score (wave per row, w staged in LDS).
// ---------------------------------------------------------------------------
__global__ void msg_score_kernel(const float* __restrict__ x,
                                 const float* __restrict__ w,
                                 const float* __restrict__ att, int att_off,
                                 float* __restrict__ msg,
                                 float* __restrict__ score,
                                 int n_rows) {
    __shared__ float wl[D_IN * D_OUT];
    const int tid = threadIdx.x;

    const float4* w4  = (const float4*)w;
    float4*       wl4 = (float4*)wl;
    for (int i = tid; i < (D_IN * D_OUT) / 4; i += blockDim.x) wl4[i] = w4[i];
    __syncthreads();

    const int gtid = blockIdx.x * blockDim.x + tid;
    const int row  = gtid >> 6;
    const int j    = tid & 63;
    if (row >= n_rows) return;

    const float4* x4 = (const float4*)(x + (size_t)row * D_IN);
    float acc = 0.f;
#pragma unroll
    for (int k4 = 0; k4 < D_IN / 4; ++k4) {
        float4 xv = x4[k4];
        acc += xv.x * wl[(k4 * 4 + 0) * D_OUT + j];
        acc += xv.y * wl[(k4 * 4 + 1) * D_OUT + j];
        acc += xv.z * wl[(k4 * 4 + 2) * D_OUT + j];
        acc += xv.w * wl[(k4 * 4 + 3) * D_OUT + j];
    }
    msg[(size_t)row * D_OUT + j] = acc;

    float v = acc * att[att_off + j];
#pragma unroll
    for (int off = 32; off > 0; off >>= 1) v += __shfl_down(v, off, 64);
    if (j == 0) score[row] = v;
}

// ---------------------------------------------------------------------------
// Sub-binned histogram over the unified (rows ++ cols) counter array.
// ---------------------------------------------------------------------------
__global__ void hist_kernel(const int* __restrict__ row_idx,
                            const int* __restrict__ col_idx,
                            int* __restrict__ cnt, int col_base, int nnz) {
    const int i = blockIdx.x * blockDim.x + threadIdx.x;
    if (i >= nnz) return;
    const int s = i & (SUB - 1);
    atomicAdd(&cnt[(row_idx[i] << SUB_SHIFT) + s], 1);
    atomicAdd(&cnt[col_base + (col_idx[i] << SUB_SHIFT) + s], 1);
}

// ---------------------------------------------------------------------------
// Hierarchical exclusive scan, 3 stages.
// ---------------------------------------------------------------------------
__global__ void scan_stage1(const int* __restrict__ cnt, int* __restrict__ bsum,
                            int n) {
    __shared__ int lds[256];
    const int t = threadIdx.x;
    const int base = blockIdx.x * SCAN_CHUNK;
    int s = 0;
    for (int k = t; k < SCAN_CHUNK; k += 256) {
        const int j = base + k;
        if (j < n) s += cnt[j];
    }
    lds[t] = s;
    __syncthreads();
    for (int d = 128; d > 0; d >>= 1) {
        if (t < d) lds[t] += lds[t + d];
        __syncthreads();
    }
    if (t == 0) bsum[blockIdx.x] = lds[0];
}

__global__ void scan_stage2(int* __restrict__ bsum, int nb) {
    __shared__ int lds[1024];
    const int t = threadIdx.x;
    const int v = (t < nb) ? bsum[t] : 0;
    lds[t] = v;
    __syncthreads();
    for (int d = 1; d < 1024; d <<= 1) {
        int u = (t >= d) ? lds[t - d] : 0;
        __syncthreads();
        lds[t] += u;
        __syncthreads();
    }
    if (t < nb) bsum[t] = lds[t] - v;   // exclusive
}

__global__ void scan_stage3(const int* __restrict__ cnt,
                            const int* __restrict__ bsum,
                            int* __restrict__ off, int* __restrict__ cur,
                            int n, int total) {
    __shared__ int lds[256];
    const int t = threadIdx.x;
    const int base = blockIdx.x * SCAN_CHUNK + t * 16;
    int c[16];
    int s = 0;
#pragma unroll
    for (int k = 0; k < 16; ++k) {
        const int j = base + k;
        c[k] = (j < n) ? cnt[j] : 0;
        s += c[k];
    }
    lds[t] = s;
    __syncthreads();
    for (int d = 1; d < 256; d <<= 1) {
        int u = (t >= d) ? lds[t - d] : 0;
        __syncthreads();
        lds[t] += u;
        __syncthreads();
    }
    int ex = bsum[blockIdx.x] + lds[t] - s;
#pragma unroll
    for (int k = 0; k < 16; ++k) {
        const int j = base + k;
        if (j < n) { off[j] = ex; cur[j] = ex; ex += c[k]; }
    }
    if (blockIdx.x == 0 && t == 0) off[n] = total;
}

// ---------------------------------------------------------------------------
// Counting-sort payload scatter, one kernel per direction (shorter dependent
// atomic->store chain per thread; separate profiling lines). 16 B records.
// ---------------------------------------------------------------------------
__global__ void scatter_row_kernel(const int* __restrict__ row_idx,
                                   const int* __restrict__ col_idx,
                                   const float* __restrict__ nbhd,
                                   const float* __restrict__ s_score,
                                   const float* __restrict__ t_score,
                                   int* __restrict__ cur,
                                   float4* __restrict__ pay, int nnz) {
    const int i = blockIdx.x * blockDim.x + threadIdx.x;
    if (i >= nnz) return;
    const int r = row_idx[i];
    const int c = col_idx[i];
    const float xv = s_score[c] + t_score[r];
    const float e  = xv >= 0.f ? xv : NEG_SLOPE * xv;
    const int p = atomicAdd(&cur[(r << SUB_SHIFT) + (i & (SUB - 1))], 1);
    pay[p] = make_float4(__int_as_float(c), e, nbhd[i], 0.f);
}

__global__ void scatter_col_kernel(const int* __restrict__ row_idx,
                                   const int* __restrict__ col_idx,
                                   const float* __restrict__ nbhd,
                                   const float* __restrict__ s_score,
                                   const float* __restrict__ t_score,
                                   int* __restrict__ cur, int col_base,
                                   float4* __restrict__ pay, int nnz) {
    const int i = blockIdx.x * blockDim.x + threadIdx.x;
    if (i >= nnz) return;
    const int r = row_idx[i];
    const int c = col_idx[i];
    const float xv = s_score[c] + t_score[r];
    const float e  = xv >= 0.f ? xv : NEG_SLOPE * xv;
    const int p = atomicAdd(&cur[col_base + (c << SUB_SHIFT) + (i & (SUB - 1))], 1);
    pay[p] = make_float4(__int_as_float(r), e, nbhd[i], 0.f);
}

// ---------------------------------------------------------------------------
// Segmented accumulate, wave per output row.
// Pass 1: f64 segment sum of e (register/shuffle, deterministic).
// Pass 2: 64-record chunks; lanes split into 4 groups of 16 -- each group
// gathers a DIFFERENT edge's msg row as float4 (16 B/lane, 4 rows = 1 KB per
// wave issue -> 4x fewer gather instructions, 4x deeper MLP). OOB lanes carry
// wt=0/o=0 so no tail guards needed. 8-shuffle butterfly folds the 4 groups;
// lanes 0-15 store one float4 each (256 B coalesced).
// ---------------------------------------------------------------------------
__global__ void accum_kernel(const int* __restrict__ off, int off_base,
                             const float4* __restrict__ pay,
                             const float* __restrict__ other_msg,
                             float* __restrict__ out, int n_mine) {
    const int wave = (int)((blockIdx.x * (size_t)blockDim.x + threadIdx.x) >> 6);
    const int lane = threadIdx.x & 63;
    if (wave >= n_mine) return;

    const int beg = off[off_base + (wave << SUB_SHIFT)];
    const int end = off[off_base + (wave << SUB_SHIFT) + SUB];

    // pass 1: f64 sum of e over the segment
    double psum = 0.0;
    for (int k = beg + lane; k < end; k += 64) psum += (double)pay[k].y;
#pragma unroll
    for (int o = 32; o > 0; o >>= 1) psum += __shfl_down(psum, o, 64);
    double ers = __shfl(psum, 0, 64);
    if (ers == 0.0) ers = 1.0;
    const double inv = 1.0 / ers;

    // pass 2: chunked gather-accumulate, 4 edges in flight per iteration
    const int g = lane >> 4;       // edge group 0..3
    const int q = lane & 15;       // quarter-row position
    const float4* msg4 = (const float4*)other_msg;
    float4 acc = make_float4(0.f, 0.f, 0.f, 0.f);

    for (int kb = beg; kb < end; kb += 64) {
        const int k = kb + lane;
        int o = 0; float wt = 0.f;
        if (k < end) {
            float4 p = pay[k];
            o  = __float_as_int(p.x);
            wt = (float)((double)p.y * inv) * p.z;
        }
        const int cnt = min(64, end - kb);
        for (int j = 0; j < cnt; j += 4) {
            const int   jj = j + g;              // <= 63 always
            const int   oj = __shfl(o,  jj, 64);
            const float wj = __shfl(wt, jj, 64); // 0 for OOB edges
            float4 m = msg4[((size_t)oj << 4) + q];
            acc.x += wj * m.x;
            acc.y += wj * m.y;
            acc.z += wj * m.z;
            acc.w += wj * m.w;
        }
    }

    // fold the 4 edge-groups (butterfly over lane bits 4,5)
#pragma unroll
    for (int d = 16; d < 64; d <<= 1) {
        acc.x += __shfl_xor(acc.x, d, 64);
        acc.y += __shfl_xor(acc.y, d, 64);
        acc.z += __shfl_xor(acc.z, d, 64);
        acc.w += __shfl_xor(acc.w, d, 64);
    }
    if (g == 0) ((float4*)out)[((size_t)wave << 4) + q] = acc;
}

// ---------------------------------------------------------------------------
extern "C" void kernel_launch(void* const* d_in, const int* in_sizes, int n_in,
                              void* d_out, int out_size, void* d_ws, size_t ws_size,
                              hipStream_t stream) {
    const float* x_source = (const float*)d_in[0];
    const float* x_target = (const float*)d_in[1];
    const float* nbhd     = (const float*)d_in[2];
    const float* w_s      = (const float*)d_in[3];
    const float* w_t      = (const float*)d_in[4];
    const float* att      = (const float*)d_in[5];
    const int*   row_idx  = (const int*)d_in[6];
    const int*   col_idx  = (const int*)d_in[7];

    const int n_s = in_sizes[0] / D_IN;   // 100000
    const int n_t = in_sizes[1] / D_IN;   // 20000
    const int nnz = in_sizes[2];          // 2000000

    float* out = (float*)d_out;
    float* mos = out;                          // (n_s, 64)
    float* mot = out + (size_t)n_s * D_OUT;    // (n_t, 64)

    const int col_base = n_t * SUB;            // 160000
    const int n_cnt    = (n_t + n_s) * SUB;    // 960000
    const int total    = 2 * nnz;              // 4000000

    // workspace layout (~108 MB)
    char* ws = (char*)d_ws;
    float* s_msg   = (float*)ws;  ws += sizeof(float) * (size_t)n_s * D_OUT;
    float* t_msg   = (float*)ws;  ws += sizeof(float) * (size_t)n_t * D_OUT;
    float* s_score = (float*)ws;  ws += sizeof(float) * (size_t)n_s;
    float* t_score = (float*)ws;  ws += sizeof(float) * (size_t)n_t;
    int* cnt  = (int*)ws;  ws += sizeof(int) * (size_t)n_cnt;
    int* cur  = (int*)ws;  ws += sizeof(int) * (size_t)n_cnt;
    int* off  = (int*)ws;  ws += sizeof(int) * (size_t)(n_cnt + 1);
    int* bsum = (int*)ws;  ws += sizeof(int) * 1024;
    ws = (char*)(((uintptr_t)ws + 15) & ~(uintptr_t)15);
    float4* pay = (float4*)ws;  ws += sizeof(float4) * (size_t)total;

    hipMemsetAsync(cnt, 0, sizeof(int) * (size_t)n_cnt, stream);

    // 1) messages + scores
    msg_score_kernel<<<(n_s * 64 + 255) / 256, 256, 0, stream>>>(
        x_source, w_s, att, 0, s_msg, s_score, n_s);
    msg_score_kernel<<<(n_t * 64 + 255) / 256, 256, 0, stream>>>(
        x_target, w_t, att, D_OUT, t_msg, t_score, n_t);

    // 2) counting sort: hist -> 3-stage scan -> payload scatter (x2)
    hist_kernel<<<(nnz + 255) / 256, 256, 0, stream>>>(
        row_idx, col_idx, cnt, col_base, nnz);

    const int nb = (n_cnt + SCAN_CHUNK - 1) / SCAN_CHUNK;   // 235
    scan_stage1<<<nb, 256, 0, stream>>>(cnt, bsum, n_cnt);
    scan_stage2<<<1, 1024, 0, stream>>>(bsum, nb);
    scan_stage3<<<nb, 256, 0, stream>>>(cnt, bsum, off, cur, n_cnt, total);

    scatter_row_kernel<<<(nnz + 255) / 256, 256, 0, stream>>>(
        row_idx, col_idx, nbhd, s_score, t_score, cur, pay, nnz);
    scatter_col_kernel<<<(nnz + 255) / 256, 256, 0, stream>>>(
        row_idx, col_idx, nbhd, s_score, t_score, cur, col_base, pay, nnz);

    // 3) segmented accumulation, no output atomics
    accum_kernel<<<(int)(((size_t)n_t * 64 + 255) / 256), 256, 0, stream>>>(
        off, 0, pay, s_msg, mot, n_t);
    accum_kernel<<<(int)(((size_t)n_s * 64 + 255) / 256), 256, 0, stream>>>(
        off, col_base, pay, t_msg, mos, n_s);
}